// Round 8
// baseline (1805.717 us; speedup 1.0000x reference)
//
#include <hip/hip_runtime.h>

#define TT 64
#define BB 4096
#define HH 256
#define BM 8              // batch elements per block
#define NBLK (BB / BM)    // 512 blocks

// d_ws layout (byte offsets)
#define WS_WHT_B   0u              // W_h^T  f32, 256KB
#define WS_WH2T_B  262144u         // W_h2^T f32, 256KB
#define WS_EMB_B   524288u         // emb f32, 256B
#define WS_REC_B   1048576u        // rec f32 [T,B,4], 4MB

__device__ __forceinline__ float clip01f(float v) {
    return fminf(fmaxf(v, 0.0f), 1.0f);
}

__device__ __forceinline__ unsigned long long rfl64(unsigned long long v) {
    unsigned lo = __builtin_amdgcn_readfirstlane((unsigned)v);
    unsigned hi = __builtin_amdgcn_readfirstlane((unsigned)(v >> 32));
    return ((unsigned long long)hi << 32) | lo;
}

// np: f64 math (int arange -> f64 promote), then asarray(dtype=float32)
__global__ __launch_bounds__(64) void setup_emb_kernel(float* __restrict__ emb) {
    int i = threadIdx.x;
    const double sigma = 64.0 / 10.0;
    const double c = 32.0;
    double d = ((double)i - c) / sigma;
    double e = exp(-0.5 * (d * d));
    double d0 = (0.0 - c) / sigma;
    double emin = exp(-0.5 * (d0 * d0));
    emb[i] = (float)((e - emin) / (1.0 - emin));   // e.max() = exp(0) = 1
}

__global__ __launch_bounds__(256) void transpose_kernel(const float* __restrict__ src,
                                                        float* __restrict__ dst) {
    __shared__ float tile[32][33];
    int tx = threadIdx.x & 31, ty = threadIdx.x >> 5;
    int bx = blockIdx.x, by = blockIdx.y;
#pragma unroll
    for (int i = 0; i < 32; i += 8)
        tile[ty + i][tx] = src[(by * 32 + ty + i) * HH + bx * 32 + tx];
    __syncthreads();
#pragma unroll
    for (int i = 0; i < 32; i += 8)
        dst[(bx * 32 + ty + i) * HH + by * 32 + tx] = tile[tx][ty + i];
}

// acc[b] += sum over active input neurons k (ascending) of WT[k*256 + n], f32
// single accumulator. Products s[k]*W are exactly {0, W}; adding 0.0f is an exact
// no-op, so this equals BLAS/Eigen's sequential-ascending fma chain over all 256 k.
__device__ __forceinline__ void accum(const float* __restrict__ WT, int n,
                                      const unsigned long long* M, float acc[BM]) {
#pragma unroll
    for (int w2 = 0; w2 < 4; ++w2) {
        unsigned long long mb[BM];
        unsigned long long un = 0;
#pragma unroll
        for (int b = 0; b < BM; ++b) { mb[b] = rfl64(M[w2 * BM + b]); un |= mb[b]; }
        if (!un) continue;
        const float* Wp = WT + (w2 << 6) * HH + n;
        int l = __builtin_ctzll(un); un &= un - 1;
        float wv = Wp[l << 8];                     // depth-2 load pipeline
        while (un) {
            int l2 = __builtin_ctzll(un); un &= un - 1;
            float wv2 = Wp[l2 << 8];
            unsigned long long bit = 1ull << l;
#pragma unroll
            for (int b = 0; b < BM; ++b) if (mb[b] & bit) acc[b] += wv;
            l = l2; wv = wv2;
        }
        unsigned long long bit = 1ull << l;
#pragma unroll
        for (int b = 0; b < BM; ++b) if (mb[b] & bit) acc[b] += wv;
    }
}

__global__ __launch_bounds__(256) void snn_main_kernel(
    const float* __restrict__ x,
    const float* __restrict__ W_in, const float* __restrict__ b_in,
    const float* __restrict__ beta_in, const float* __restrict__ thr_in,
    const float* __restrict__ b_h, const float* __restrict__ beta_h, const float* __restrict__ thr_h,
    const float* __restrict__ b_h2, const float* __restrict__ beta_h2, const float* __restrict__ thr_h2,
    const float* __restrict__ W_out, const float* __restrict__ b_out, const float* __restrict__ beta_out,
    const float* __restrict__ WhT, const float* __restrict__ Wh2T,
    const float* __restrict__ emb, float* __restrict__ rec)
{
#pragma clang fp contract(off)   // all contraction EXPLICIT via fmaf below
    const int tid = threadIdx.x;
    const int n = tid;                  // thread = neuron
    const int w = tid >> 6, lane = tid & 63;
    const int b0 = blockIdx.x * BM;

    __shared__ unsigned long long M1[4][BM], M2[4][BM], M3L[4][BM];
    __shared__ float WoutS[2][HH];
    WoutS[0][n] = W_out[n];
    WoutS[1][n] = W_out[HH + n];

    float bi  = b_in[n];
    float bt1 = clip01f(beta_in[n]), th1 = thr_in[n];
    float bh  = b_h[n];
    float bt2 = clip01f(beta_h[n]),  th2 = thr_h[n];
    float bh2v = b_h2[n];
    float bt3 = clip01f(beta_h2[n]), th3 = thr_h2[n];
    float wi0 = W_in[n * 3], wi1 = W_in[n * 3 + 1], wi2 = W_in[n * 3 + 2];

    const int ob = (tid >> 1) & 7;      // output-stage batch (wave 0)
    const int oo = tid & 1;             // output channel
    float bto = clip01f(beta_out[oo]);
    float bo  = b_out[oo];

    float m1[BM], m2[BM], m4[BM], acc[BM];
#pragma unroll
    for (int b = 0; b < BM; ++b) { m1[b] = 0.f; m2[b] = 0.f; m4[b] = 0.f; }
    float m3s = 0.f;

    for (int t = 0; t < TT; ++t) {
        float et = emb[t];
        float xf[24];
        const float4* xp = (const float4*)(x + (size_t)(t * BB + b0) * 3);
#pragma unroll
        for (int i = 0; i < 6; ++i) *(float4*)(xf + 4 * i) = xp[i];

        bool s[BM];

        // ---- layer 1: ascending-k fma dot (gemm form), bias after;
        //      LIF with XLA-contracted update:
        //      mm = fma(-reset, thr, fma(beta, m, cur)) ----
#pragma unroll
        for (int b = 0; b < BM; ++b) {
            float xe0 = xf[b * 3 + 0] * et;        // x*emb rounded first (array op)
            float xe1 = xf[b * 3 + 1] * et;
            float xe2 = xf[b * 3 + 2] * et;
            float a1 = xe0 * wi0;                  // == fma(xe0,wi0,0)
            a1 = fmaf(xe1, wi1, a1);
            a1 = fmaf(xe2, wi2, a1);
            float cur = a1 + bi;
            float rf = ((m1[b] - th1) > 0.f) ? 1.f : 0.f;   // reset from PREVIOUS mem
            float mm = fmaf(bt1, m1[b], cur);      // contracted: beta*m + cur
            mm = fmaf(-rf, th1, mm);               // contracted: - reset*thr
            m1[b] = mm;
            s[b] = (mm - th1) > 0.f;
        }
#pragma unroll
        for (int b = 0; b < BM; ++b) {
            unsigned long long mk = __ballot(s[b]);
            if (lane == 0) M1[w][b] = mk;
        }
        __syncthreads();

        // ---- layer 2 ----
#pragma unroll
        for (int b = 0; b < BM; ++b) acc[b] = 0.f;
        accum(WhT, n, &M1[0][0], acc);
#pragma unroll
        for (int b = 0; b < BM; ++b) {
            float cur = acc[b] + bh;
            float rf = ((m2[b] - th2) > 0.f) ? 1.f : 0.f;
            float mm = fmaf(bt2, m2[b], cur);
            mm = fmaf(-rf, th2, mm);
            m2[b] = mm;
            s[b] = (mm - th2) > 0.f;
        }
#pragma unroll
        for (int b = 0; b < BM; ++b) {
            unsigned long long mk = __ballot(s[b]);
            if (lane == 0) M2[w][b] = mk;
        }
        __syncthreads();

        // ---- layer 3 ----
#pragma unroll
        for (int b = 0; b < BM; ++b) acc[b] = 0.f;
        accum(Wh2T, n, &M2[0][0], acc);
#pragma unroll
        for (int b = 0; b < BM; ++b) {
            float cur = acc[b] + bh2v;
            float rf = ((m4[b] - th3) > 0.f) ? 1.f : 0.f;
            float mm = fmaf(bt3, m4[b], cur);
            mm = fmaf(-rf, th3, mm);
            m4[b] = mm;
            s[b] = (mm - th3) > 0.f;
        }
#pragma unroll
        for (int b = 0; b < BM; ++b) {
            unsigned long long mk = __ballot(s[b]);
            if (lane == 0) M3L[w][b] = mk;
        }
        __syncthreads();

        // ---- li_out: ascending sequential dot; contracted update:
        //      m3 = fma(beta_out, m3, dot) + b_out ----
        if (w == 0) {
            float p = 0.f;
#pragma unroll
            for (int w2 = 0; w2 < 4; ++w2) {
                unsigned long long mk = M3L[w2][ob];
                const float* wrow = &WoutS[oo][w2 << 6];
                while (mk) {
                    int l = __builtin_ctzll(mk); mk &= mk - 1;
                    p = p + wrow[l];
                }
            }
            float mm3 = fmaf(bto, m3s, p);         // contracted: beta*m3 + dot
            mm3 = mm3 + bo;                        // then + b_out
            m3s = mm3;
            float spk = ((m3s - 1.0f) > 0.f) ? 1.f : 0.f;
            float om3 = __shfl_xor(m3s, 1, 64);
            float osp = __shfl_xor(spk, 1, 64);
            if (tid < 16 && oo == 0) {             // rec[t, b0+ob, :] = {spk0, spk1, m30, m31}
                *(float4*)(rec + ((size_t)t * BB + b0 + ob) * 4) =
                    make_float4(spk, osp, m3s, om3);
            }
        }
    }
}

// out[r,o] = (ascending-k fma dot) + b_pred[o]   (gemm form)
__global__ __launch_bounds__(256) void pred_kernel(
    const float* __restrict__ rec, const float* __restrict__ W_pred,
    const float* __restrict__ b_pred, float* __restrict__ out)
{
#pragma clang fp contract(off)
    int r = blockIdx.x * 256 + threadIdx.x;   // 0..4095
    const float* f = rec + (size_t)r * 256;
    float a0 = 0.f, a1 = 0.f;
#pragma unroll 4
    for (int c = 0; c < 256; ++c) {
        float v = f[c];
        a0 = fmaf(v, W_pred[c], a0);
        a1 = fmaf(v, W_pred[256 + c], a1);
    }
    out[r * 2 + 0] = a0 + b_pred[0];
    out[r * 2 + 1] = a1 + b_pred[1];
}

extern "C" void kernel_launch(void* const* d_in, const int* in_sizes, int n_in,
                              void* d_out, int out_size, void* d_ws, size_t ws_size,
                              hipStream_t stream)
{
    const float* x        = (const float*)d_in[0];
    const float* W_in     = (const float*)d_in[1];
    const float* b_in     = (const float*)d_in[2];
    const float* beta_in  = (const float*)d_in[3];
    const float* thr_in   = (const float*)d_in[4];
    const float* W_h      = (const float*)d_in[5];
    const float* b_h      = (const float*)d_in[6];
    const float* beta_h   = (const float*)d_in[7];
    const float* thr_h    = (const float*)d_in[8];
    const float* W_h2     = (const float*)d_in[9];
    const float* b_h2     = (const float*)d_in[10];
    const float* beta_h2  = (const float*)d_in[11];
    const float* thr_h2   = (const float*)d_in[12];
    const float* W_out    = (const float*)d_in[13];
    const float* b_out    = (const float*)d_in[14];
    const float* beta_out = (const float*)d_in[15];
    const float* W_pred   = (const float*)d_in[16];
    const float* b_pred   = (const float*)d_in[17];

    char* ws = (char*)d_ws;
    float* WhT  = (float*)(ws + WS_WHT_B);
    float* Wh2T = (float*)(ws + WS_WH2T_B);
    float* emb  = (float*)(ws + WS_EMB_B);
    float* rec  = (float*)(ws + WS_REC_B);

    dim3 tgrid(8, 8);
    transpose_kernel<<<tgrid, 256, 0, stream>>>(W_h, WhT);
    transpose_kernel<<<tgrid, 256, 0, stream>>>(W_h2, Wh2T);
    setup_emb_kernel<<<1, 64, 0, stream>>>(emb);

    snn_main_kernel<<<NBLK, 256, 0, stream>>>(
        x, W_in, b_in, beta_in, thr_in,
        b_h, beta_h, thr_h,
        b_h2, beta_h2, thr_h2,
        W_out, b_out, beta_out,
        WhT, Wh2T, emb, rec);

    pred_kernel<<<BB / 256, 256, 0, stream>>>(rec, W_pred, b_pred, (float*)d_out);
}

// Round 9
// 1744.517 us; speedup vs baseline: 1.0351x; 1.0351x over previous
//
#include <hip/hip_runtime.h>

#define TT 64
#define BB 4096
#define HH 256
#define BM 4              // batch elements per block
#define NBLK (BB / BM)    // 1024 blocks -> 4 blocks/CU, ~43% occupancy

// d_ws layout (byte offsets)
#define WS_WHT_B   0u              // W_h^T  f32, 256KB
#define WS_WH2T_B  262144u         // W_h2^T f32, 256KB
#define WS_EMB_B   524288u         // emb f32, 256B
#define WS_REC_B   1048576u        // rec f32 [T,B,4], 4MB

__device__ __forceinline__ float clip01f(float v) {
    return fminf(fmaxf(v, 0.0f), 1.0f);
}

__device__ __forceinline__ unsigned long long rfl64(unsigned long long v) {
    unsigned lo = __builtin_amdgcn_readfirstlane((unsigned)v);
    unsigned hi = __builtin_amdgcn_readfirstlane((unsigned)(v >> 32));
    return ((unsigned long long)hi << 32) | lo;
}

__global__ __launch_bounds__(64) void setup_emb_kernel(float* __restrict__ emb) {
    int i = threadIdx.x;
    const double sigma = 64.0 / 10.0;
    const double c = 32.0;
    double d = ((double)i - c) / sigma;
    double e = exp(-0.5 * (d * d));
    double d0 = (0.0 - c) / sigma;
    double emin = exp(-0.5 * (d0 * d0));
    emb[i] = (float)((e - emin) / (1.0 - emin));   // e.max() = exp(0) = 1
}

__global__ __launch_bounds__(256) void transpose_kernel(const float* __restrict__ src,
                                                        float* __restrict__ dst) {
    __shared__ float tile[32][33];
    int tx = threadIdx.x & 31, ty = threadIdx.x >> 5;
    int bx = blockIdx.x, by = blockIdx.y;
#pragma unroll
    for (int i = 0; i < 32; i += 8)
        tile[ty + i][tx] = src[(by * 32 + ty + i) * HH + bx * 32 + tx];
    __syncthreads();
#pragma unroll
    for (int i = 0; i < 32; i += 8)
        dst[(bx * 32 + ty + i) * HH + by * 32 + tx] = tile[tx][ty + i];
}

// acc[b] += sum over active input neurons k (ascending) of WT[k*256 + n].
// Gating via fmaf with a wave-uniform scalar sel in {1.0, 0.0}:
//   fmaf(1,w,acc) == RN(acc+w)  (bit-equal to the add)
//   fmaf(0,w,acc) == acc        (exact no-op)
// -> 1 VALU + 2 SALU per (bit,batch) instead of 2 VALU. Ascending-k order kept,
// so each (n,b) chain is bit-identical to BLAS's sequential fma accumulation.
__device__ __forceinline__ void accum(const float* __restrict__ WT, int n,
                                      const unsigned long long* M, float acc[BM]) {
#pragma unroll
    for (int w2 = 0; w2 < 4; ++w2) {
        unsigned long long mb[BM];
        unsigned long long un = 0;
#pragma unroll
        for (int b = 0; b < BM; ++b) { mb[b] = rfl64(M[w2 * BM + b]); un |= mb[b]; }
        if (!un) continue;
        const float* Wp = WT + (w2 << 6) * HH + n;
        int l = __builtin_ctzll(un); un &= un - 1;
        float wv = Wp[l << 8];                     // depth-2 load pipeline
        unsigned long long bit = 1ull << l;
        while (un) {
            int l2 = __builtin_ctzll(un); un &= un - 1;
            float wv2 = Wp[l2 << 8];
#pragma unroll
            for (int b = 0; b < BM; ++b) {
                float sel = (mb[b] & bit) ? 1.0f : 0.0f;   // scalar cselect (uniform)
                acc[b] = fmaf(sel, wv, acc[b]);            // exact gated add
            }
            bit = 1ull << l2; wv = wv2;
        }
#pragma unroll
        for (int b = 0; b < BM; ++b) {
            float sel = (mb[b] & bit) ? 1.0f : 0.0f;
            acc[b] = fmaf(sel, wv, acc[b]);
        }
    }
}

__global__ __launch_bounds__(256, 4) void snn_main_kernel(
    const float* __restrict__ x,
    const float* __restrict__ W_in, const float* __restrict__ b_in,
    const float* __restrict__ beta_in, const float* __restrict__ thr_in,
    const float* __restrict__ b_h, const float* __restrict__ beta_h, const float* __restrict__ thr_h,
    const float* __restrict__ b_h2, const float* __restrict__ beta_h2, const float* __restrict__ thr_h2,
    const float* __restrict__ W_out, const float* __restrict__ b_out, const float* __restrict__ beta_out,
    const float* __restrict__ WhT, const float* __restrict__ Wh2T,
    const float* __restrict__ emb, float* __restrict__ rec)
{
#pragma clang fp contract(off)   // all contraction EXPLICIT via fmaf below
    const int tid = threadIdx.x;
    const int n = tid;                  // thread = neuron
    const int w = tid >> 6, lane = tid & 63;
    const int b0 = blockIdx.x * BM;

    __shared__ unsigned long long M1[4][BM], M2[4][BM], M3L[4][BM];
    __shared__ float WoutS[2][HH];
    WoutS[0][n] = W_out[n];
    WoutS[1][n] = W_out[HH + n];

    float bi  = b_in[n];
    float bt1 = clip01f(beta_in[n]), th1 = thr_in[n];
    float bh  = b_h[n];
    float bt2 = clip01f(beta_h[n]),  th2 = thr_h[n];
    float bh2v = b_h2[n];
    float bt3 = clip01f(beta_h2[n]), th3 = thr_h2[n];
    float wi0 = W_in[n * 3], wi1 = W_in[n * 3 + 1], wi2 = W_in[n * 3 + 2];

    const int ob = (tid >> 1) & (BM - 1);   // output-stage batch (wave 0, tid<2*BM)
    const int oo = tid & 1;                 // output channel
    float bto = clip01f(beta_out[oo]);
    float bo  = b_out[oo];

    float m1[BM], m2[BM], m4[BM], acc[BM];
#pragma unroll
    for (int b = 0; b < BM; ++b) { m1[b] = 0.f; m2[b] = 0.f; m4[b] = 0.f; }
    float m3s = 0.f;

    for (int t = 0; t < TT; ++t) {
        float et = emb[t];
        float xf[BM * 3];
        const float4* xp = (const float4*)(x + (size_t)(t * BB + b0) * 3);
#pragma unroll
        for (int i = 0; i < (BM * 3) / 4; ++i) *(float4*)(xf + 4 * i) = xp[i];

        bool s[BM];

        // ---- layer 1: ascending-k fma dot, bias after; contracted LIF update ----
#pragma unroll
        for (int b = 0; b < BM; ++b) {
            float xe0 = xf[b * 3 + 0] * et;
            float xe1 = xf[b * 3 + 1] * et;
            float xe2 = xf[b * 3 + 2] * et;
            float a1 = xe0 * wi0;                  // == fma(xe0,wi0,0)
            a1 = fmaf(xe1, wi1, a1);
            a1 = fmaf(xe2, wi2, a1);
            float cur = a1 + bi;
            float rf = ((m1[b] - th1) > 0.f) ? 1.f : 0.f;   // reset from PREVIOUS mem
            float mm = fmaf(bt1, m1[b], cur);      // contracted: beta*m + cur
            mm = fmaf(-rf, th1, mm);               // contracted: - reset*thr
            m1[b] = mm;
            s[b] = (mm - th1) > 0.f;
        }
#pragma unroll
        for (int b = 0; b < BM; ++b) {
            unsigned long long mk = __ballot(s[b]);
            if (lane == 0) M1[w][b] = mk;
        }
        __syncthreads();

        // ---- layer 2 ----
#pragma unroll
        for (int b = 0; b < BM; ++b) acc[b] = 0.f;
        accum(WhT, n, &M1[0][0], acc);
#pragma unroll
        for (int b = 0; b < BM; ++b) {
            float cur = acc[b] + bh;
            float rf = ((m2[b] - th2) > 0.f) ? 1.f : 0.f;
            float mm = fmaf(bt2, m2[b], cur);
            mm = fmaf(-rf, th2, mm);
            m2[b] = mm;
            s[b] = (mm - th2) > 0.f;
        }
#pragma unroll
        for (int b = 0; b < BM; ++b) {
            unsigned long long mk = __ballot(s[b]);
            if (lane == 0) M2[w][b] = mk;
        }
        __syncthreads();

        // ---- layer 3 ----
#pragma unroll
        for (int b = 0; b < BM; ++b) acc[b] = 0.f;
        accum(Wh2T, n, &M2[0][0], acc);
#pragma unroll
        for (int b = 0; b < BM; ++b) {
            float cur = acc[b] + bh2v;
            float rf = ((m4[b] - th3) > 0.f) ? 1.f : 0.f;
            float mm = fmaf(bt3, m4[b], cur);
            mm = fmaf(-rf, th3, mm);
            m4[b] = mm;
            s[b] = (mm - th3) > 0.f;
        }
#pragma unroll
        for (int b = 0; b < BM; ++b) {
            unsigned long long mk = __ballot(s[b]);
            if (lane == 0) M3L[w][b] = mk;
        }
        __syncthreads();

        // ---- li_out: ascending sequential dot; contracted:
        //      m3 = fma(beta_out, m3, dot) + b_out ----
        if (w == 0) {
            float p = 0.f;
#pragma unroll
            for (int w2 = 0; w2 < 4; ++w2) {
                unsigned long long mk = M3L[w2][ob];
                const float* wrow = &WoutS[oo][w2 << 6];
                while (mk) {
                    int l = __builtin_ctzll(mk); mk &= mk - 1;
                    p = p + wrow[l];
                }
            }
            float mm3 = fmaf(bto, m3s, p);
            mm3 = mm3 + bo;
            m3s = mm3;
            float spk = ((m3s - 1.0f) > 0.f) ? 1.f : 0.f;
            float om3 = __shfl_xor(m3s, 1, 64);
            float osp = __shfl_xor(spk, 1, 64);
            if (tid < 2 * BM && oo == 0) {         // rec[t, b0+ob, :] = {spk0, spk1, m30, m31}
                *(float4*)(rec + ((size_t)t * BB + b0 + ob) * 4) =
                    make_float4(spk, osp, m3s, om3);
            }
        }
    }
}

// out[r,o] = (ascending-k fma dot) + b_pred[o]   (gemm form)
__global__ __launch_bounds__(256) void pred_kernel(
    const float* __restrict__ rec, const float* __restrict__ W_pred,
    const float* __restrict__ b_pred, float* __restrict__ out)
{
#pragma clang fp contract(off)
    int r = blockIdx.x * 256 + threadIdx.x;   // 0..4095
    const float* f = rec + (size_t)r * 256;
    float a0 = 0.f, a1 = 0.f;
#pragma unroll 4
    for (int c = 0; c < 256; ++c) {
        float v = f[c];
        a0 = fmaf(v, W_pred[c], a0);
        a1 = fmaf(v, W_pred[256 + c], a1);
    }
    out[r * 2 + 0] = a0 + b_pred[0];
    out[r * 2 + 1] = a1 + b_pred[1];
}

extern "C" void kernel_launch(void* const* d_in, const int* in_sizes, int n_in,
                              void* d_out, int out_size, void* d_ws, size_t ws_size,
                              hipStream_t stream)
{
    const float* x        = (const float*)d_in[0];
    const float* W_in     = (const float*)d_in[1];
    const float* b_in     = (const float*)d_in[2];
    const float* beta_in  = (const float*)d_in[3];
    const float* thr_in   = (const float*)d_in[4];
    const float* W_h      = (const float*)d_in[5];
    const float* b_h      = (const float*)d_in[6];
    const float* beta_h   = (const float*)d_in[7];
    const float* thr_h    = (const float*)d_in[8];
    const float* W_h2     = (const float*)d_in[9];
    const float* b_h2     = (const float*)d_in[10];
    const float* beta_h2  = (const float*)d_in[11];
    const float* thr_h2   = (const float*)d_in[12];
    const float* W_out    = (const float*)d_in[13];
    const float* b_out    = (const float*)d_in[14];
    const float* beta_out = (const float*)d_in[15];
    const float* W_pred   = (const float*)d_in[16];
    const float* b_pred   = (const float*)d_in[17];

    char* ws = (char*)d_ws;
    float* WhT  = (float*)(ws + WS_WHT_B);
    float* Wh2T = (float*)(ws + WS_WH2T_B);
    float* emb  = (float*)(ws + WS_EMB_B);
    float* rec  = (float*)(ws + WS_REC_B);

    dim3 tgrid(8, 8);
    transpose_kernel<<<tgrid, 256, 0, stream>>>(W_h, WhT);
    transpose_kernel<<<tgrid, 256, 0, stream>>>(W_h2, Wh2T);
    setup_emb_kernel<<<1, 64, 0, stream>>>(emb);

    snn_main_kernel<<<NBLK, 256, 0, stream>>>(
        x, W_in, b_in, beta_in, thr_in,
        b_h, beta_h, thr_h,
        b_h2, beta_h2, thr_h2,
        W_out, b_out, beta_out,
        WhT, Wh2T, emb, rec);

    pred_kernel<<<BB / 256, 256, 0, stream>>>(rec, W_pred, b_pred, (float*)d_out);
}